// Round 11
// baseline (340.996 us; speedup 1.0000x reference)
//
#include <hip/hip_runtime.h>
#include <hip/hip_bf16.h>
#include <math.h>

#define N_NODES 50000
#define N_EDGES 1600000
#define TE 64
#define NB_SCAN 196   // ceil(50000/256)
#define LOG2E 1.44269504088896340736f
#define SC_CHUNK 2048
#define NSEG 8        // dst-range segments (one per XCD)
#define SEG_W (N_NODES / NSEG)   // 6250

typedef int vint4 __attribute__((ext_vector_type(4)));

// ---------------- node transform ----------------
// h = concat(x, cos(t*omega+phase)) @ W ; also s_src[n,h], s_dst[n,h] (pre-scaled
// by log2e). Register-tiled GEMM: block = 64 nodes x 64 cols, 256 thr = 16x16,
// thread tile 4 nodes x 4 cols.
template<int IN_DIM>
__global__ __launch_bounds__(256) void transform_kernel(
    const float* __restrict__ xin, const float* __restrict__ tim,
    const float* __restrict__ omega, const float* __restrict__ phase,
    const float* __restrict__ W, const float* __restrict__ asrc,
    const float* __restrict__ adst,
    float* __restrict__ hfeat, float* __restrict__ s_src, float* __restrict__ s_dst)
{
    constexpr int K = IN_DIM + TE;
    constexpr int KC = 32;             // k-chunk
    constexpr int NCH = K / KC;
    constexpr int BN = 64;             // nodes per block
    __shared__ float aS[KC][68];       // transposed a-chunk (padded row: 272B)
    __shared__ float wS[KC][64];
    __shared__ float tS[BN];

    const int tid = threadIdx.x;
    const int base = blockIdx.x * BN;

    if (tid < BN) {
        int n = base + tid;
        tS[tid] = (n < N_NODES) ? tim[n] : 0.f;
    }

    const int ty = tid >> 4;           // node quad: nodes ty*4 .. ty*4+3
    const int tx = tid & 15;           // col slot: cols tx*4 .. tx*4+3

    float acc[4][4] = {};

    for (int ch = 0; ch < NCH; ++ch) {
        const int kg0 = ch * KC;
        __syncthreads();               // previous chunk fully consumed

        // stage W chunk: 32x64 floats = 512 float4, 2 per thread (coalesced)
        #pragma unroll
        for (int j = 0; j < 2; ++j) {
            int idx = tid + j * 256;                    // float4 index
            int kk = idx >> 4, c4 = idx & 15;
            *(float4*)&wS[kk][c4 * 4] =
                ((const float4*)(W + (size_t)(kg0 + kk) * 64))[c4];
        }

        // stage a chunk (transposed)
        if (kg0 < IN_DIM) {
            #pragma unroll
            for (int j = 0; j < 2; ++j) {
                int idx = tid + j * 256;
                int nl = idx >> 3, kk = (idx & 7) * 4;
                int n = base + nl;
                float4 v = (n < N_NODES)
                    ? ((const float4*)(xin + (size_t)n * IN_DIM + kg0))[idx & 7]
                    : make_float4(0.f, 0.f, 0.f, 0.f);
                aS[kk + 0][nl] = v.x;
                aS[kk + 1][nl] = v.y;
                aS[kk + 2][nl] = v.z;
                aS[kk + 3][nl] = v.w;
            }
        } else {
            #pragma unroll
            for (int j = 0; j < 8; ++j) {
                int idx = tid + j * 256;
                int kk = idx >> 6, nl = idx & 63;
                int kg = kg0 + kk - IN_DIM;
                aS[kk][nl] = cosf(tS[nl] * omega[kg] + phase[kg]);
            }
        }
        __syncthreads();

        #pragma unroll
        for (int k = 0; k < KC; ++k) {
            const float4 av = *(const float4*)&aS[k][ty * 4];
            const float4 wv = *(const float4*)&wS[k][tx * 4];
            acc[0][0] = fmaf(av.x, wv.x, acc[0][0]);
            acc[0][1] = fmaf(av.x, wv.y, acc[0][1]);
            acc[0][2] = fmaf(av.x, wv.z, acc[0][2]);
            acc[0][3] = fmaf(av.x, wv.w, acc[0][3]);
            acc[1][0] = fmaf(av.y, wv.x, acc[1][0]);
            acc[1][1] = fmaf(av.y, wv.y, acc[1][1]);
            acc[1][2] = fmaf(av.y, wv.z, acc[1][2]);
            acc[1][3] = fmaf(av.y, wv.w, acc[1][3]);
            acc[2][0] = fmaf(av.z, wv.x, acc[2][0]);
            acc[2][1] = fmaf(av.z, wv.y, acc[2][1]);
            acc[2][2] = fmaf(av.z, wv.z, acc[2][2]);
            acc[2][3] = fmaf(av.z, wv.w, acc[2][3]);
            acc[3][0] = fmaf(av.w, wv.x, acc[3][0]);
            acc[3][1] = fmaf(av.w, wv.y, acc[3][1]);
            acc[3][2] = fmaf(av.w, wv.z, acc[3][2]);
            acc[3][3] = fmaf(av.w, wv.w, acc[3][3]);
        }
    }

    // epilogue: hfeat stores + per-head scores
    const float4 as = ((const float4*)asrc)[tx];
    const float4 ad = ((const float4*)adst)[tx];
    #pragma unroll
    for (int j = 0; j < 4; ++j) {
        const int n = base + ty * 4 + j;
        if (n < N_NODES) {
            *(float4*)(hfeat + (size_t)n * 64 + tx * 4) =
                make_float4(acc[j][0], acc[j][1], acc[j][2], acc[j][3]);
        }
        float vs = acc[j][0] * as.x + acc[j][1] * as.y
                 + acc[j][2] * as.z + acc[j][3] * as.w;
        float vd = acc[j][0] * ad.x + acc[j][1] * ad.y
                 + acc[j][2] * ad.z + acc[j][3] * ad.w;
        vs += __shfl_xor(vs, 1, 64); vs += __shfl_xor(vs, 2, 64);
        vd += __shfl_xor(vd, 1, 64); vd += __shfl_xor(vd, 2, 64);
        if ((tx & 3) == 0 && n < N_NODES) {
            s_src[n * 4 + (tx >> 2)] = vs * LOG2E;   // exp2 domain
            s_dst[n * 4 + (tx >> 2)] = vd * LOG2E;
        }
    }
}

// ---------------- CSR build ----------------
// Count-only XCD-affine hist: block tag (blockIdx%8) owns one dst-range
// segment; non-returning atomics to deg[lo,hi) stay in the owning XCD's L2.
// dst scanned NON-TEMPORALLY (streaming reads must not evict the resident
// deg lines / later epair lines from L2).
__global__ __launch_bounds__(256) void hist_kernel(
    const int* __restrict__ dst, int* __restrict__ deg)
{
    const int seg = blockIdx.x & (NSEG - 1);
    const int lo = seg * SEG_W, hi = lo + SEG_W;
    const int base = (blockIdx.x >> 3) * SC_CHUNK;
    const int end = (base + SC_CHUNK < N_EDGES) ? base + SC_CHUNK : N_EDGES;
    const int n4 = (end - base) >> 2;
    const vint4* d4p = (const vint4*)(dst + base);
    for (int q = threadIdx.x; q < n4; q += 256) {
        vint4 d4 = __builtin_nontemporal_load(d4p + q);
        if (d4.x >= lo && d4.x < hi) atomicAdd(deg + d4.x, 1);
        if (d4.y >= lo && d4.y < hi) atomicAdd(deg + d4.y, 1);
        if (d4.z >= lo && d4.z < hi) atomicAdd(deg + d4.z, 1);
        if (d4.w >= lo && d4.w < hi) atomicAdd(deg + d4.w, 1);
    }
}

__global__ __launch_bounds__(256) void scanA_kernel(
    const int* __restrict__ deg, int* __restrict__ bsum)
{
    __shared__ int sd[4];
    int i = blockIdx.x * 256 + threadIdx.x;
    int v = (i < N_NODES) ? deg[i] : 0;
    #pragma unroll
    for (int off = 32; off; off >>= 1) v += __shfl_xor(v, off, 64);
    if ((threadIdx.x & 63) == 0) sd[threadIdx.x >> 6] = v;
    __syncthreads();
    if (threadIdx.x == 0) bsum[blockIdx.x] = sd[0] + sd[1] + sd[2] + sd[3];
}

__global__ __launch_bounds__(256) void scanB_kernel(int* __restrict__ bsum)
{
    __shared__ int s[256];
    int t = threadIdx.x;
    int v = (t < NB_SCAN) ? bsum[t] : 0;
    s[t] = v;
    __syncthreads();
    #pragma unroll
    for (int off = 1; off < 256; off <<= 1) {
        int u = (t >= off) ? s[t - off] : 0;
        __syncthreads();
        s[t] += u;
        __syncthreads();
    }
    if (t < NB_SCAN) bsum[t] = s[t] - v;   // exclusive
}

__global__ __launch_bounds__(256) void scanC_kernel(
    const int* __restrict__ deg, const int* __restrict__ bsum,
    int* __restrict__ rowptr, int* __restrict__ cursor)
{
    __shared__ int s[256];
    int t = threadIdx.x;
    int i = blockIdx.x * 256 + t;
    int v = (i < N_NODES) ? deg[i] : 0;
    s[t] = v;
    __syncthreads();
    #pragma unroll
    for (int off = 1; off < 256; off <<= 1) {
        int u = (t >= off) ? s[t - off] : 0;
        __syncthreads();
        s[t] += u;
        __syncthreads();
    }
    int excl = s[t] - v + bsum[blockIdx.x];
    if (i < N_NODES) { rowptr[i] = excl; cursor[i] = excl; }
}

// XCD-affine scatter with cursor atomics. All streaming inputs (dst, src, ew)
// are read NON-TEMPORALLY so the owning XCD's L2 retains only {cursor 25KB +
// epair slice 1.6MB}; random 8B epair writes then merge into full 64B lines
// before a single writeback (round-10 regression: temporal dst stream evicted
// partially-filled epair lines -> 7x write amplification).
__global__ __launch_bounds__(256) void scatter_kernel(
    const int* __restrict__ dst, const int* __restrict__ src,
    const float* __restrict__ ew, int* __restrict__ cursor,
    int2* __restrict__ epair)
{
    const int seg = blockIdx.x & (NSEG - 1);
    const int lo = seg * SEG_W, hi = lo + SEG_W;
    const int base = (blockIdx.x >> 3) * SC_CHUNK;
    const int end = (base + SC_CHUNK < N_EDGES) ? base + SC_CHUNK : N_EDGES;
    const int n4 = (end - base) >> 2;
    const vint4* d4p = (const vint4*)(dst + base);
    for (int q = threadIdx.x; q < n4; q += 256) {
        vint4 d4 = __builtin_nontemporal_load(d4p + q);
        const int e0 = base + q * 4;
        #pragma unroll
        for (int j = 0; j < 4; ++j) {
            const int d = j == 0 ? d4.x : j == 1 ? d4.y : j == 2 ? d4.z : d4.w;
            if (d >= lo && d < hi) {
                int s = __builtin_nontemporal_load(src + e0 + j);
                float w = __builtin_nontemporal_load(ew + e0 + j);
                int pos = atomicAdd(cursor + d, 1);
                epair[pos] = make_int2(s, __float_as_int(w));
            }
        }
    }
}

// ---------------- fused per-dst aggregation ----------------
// one wave per node; 8 subgroups x 8 lanes, 8 edges in flight;
// each lane holds 8 features (two float4): cols [sl*8, sl*8+8).
// no max-subtraction (scores O(1), softmax is shift-invariant); exp2 domain.
template<int FINAL>
__global__ __launch_bounds__(256) void aggregate_kernel(
    const int* __restrict__ rowptr, const int* __restrict__ deg,
    const int2* __restrict__ epair,
    const float* __restrict__ s_src, const float* __restrict__ s_dst,
    const float* __restrict__ hfeat,
    const float* __restrict__ whead, const float* __restrict__ bhead,
    float* __restrict__ outp)
{
    const int n = blockIdx.x * 4 + (threadIdx.x >> 6);
    if (n >= N_NODES) return;
    const int lane = threadIdx.x & 63;
    const int g = lane >> 3;          // subgroup (edge slot 0..7)
    const int sl = lane & 7;          // feature octet
    const int hh = sl >> 1;           // head of my features
    const float sdst = s_dst[n * 4 + hh];
    const int beg = rowptr[n];
    const int cnt = deg[n];

    float den = 0.f;
    float4 a0 = make_float4(0.f, 0.f, 0.f, 0.f);
    float4 a1 = make_float4(0.f, 0.f, 0.f, 0.f);

    int i = g;
    int2 ep = (i < cnt) ? epair[beg + i] : make_int2(0, 0);
    while (i < cnt) {
        const int inext = i + 8;
        int2 epn = (inext < cnt) ? epair[beg + inext] : make_int2(0, 0);
        const int s = ep.x;
        const float w = __int_as_float(ep.y);
        float sc = s_src[(size_t)s * 4 + hh] + sdst;
        sc = fmaxf(sc, 0.2f * sc);                       // leaky relu (log2 domain)
        const float p = __builtin_amdgcn_exp2f(sc) * w;
        const float4* hp = (const float4*)(hfeat + (size_t)s * 64 + sl * 8);
        const float4 h0 = hp[0];
        const float4 h1 = hp[1];
        den += p;
        a0.x = fmaf(p, h0.x, a0.x); a0.y = fmaf(p, h0.y, a0.y);
        a0.z = fmaf(p, h0.z, a0.z); a0.w = fmaf(p, h0.w, a0.w);
        a1.x = fmaf(p, h1.x, a1.x); a1.y = fmaf(p, h1.y, a1.y);
        a1.z = fmaf(p, h1.z, a1.z); a1.w = fmaf(p, h1.w, a1.w);
        ep = epn; i = inext;
    }

    // merge 8 subgroups (lane bits 3,4,5)
    #pragma unroll
    for (int off = 8; off <= 32; off <<= 1) {
        den  += __shfl_xor(den, off, 64);
        a0.x += __shfl_xor(a0.x, off, 64); a0.y += __shfl_xor(a0.y, off, 64);
        a0.z += __shfl_xor(a0.z, off, 64); a0.w += __shfl_xor(a0.w, off, 64);
        a1.x += __shfl_xor(a1.x, off, 64); a1.y += __shfl_xor(a1.y, off, 64);
        a1.z += __shfl_xor(a1.z, off, 64); a1.w += __shfl_xor(a1.w, off, 64);
    }

    const float inv = 1.f / (den + 1e-16f);
    if (!FINAL) {
        if (g == 0) {
            float4 v0, v1;
            v0.x = a0.x * inv; v0.x = v0.x > 0.f ? v0.x : expm1f(v0.x);
            v0.y = a0.y * inv; v0.y = v0.y > 0.f ? v0.y : expm1f(v0.y);
            v0.z = a0.z * inv; v0.z = v0.z > 0.f ? v0.z : expm1f(v0.z);
            v0.w = a0.w * inv; v0.w = v0.w > 0.f ? v0.w : expm1f(v0.w);
            v1.x = a1.x * inv; v1.x = v1.x > 0.f ? v1.x : expm1f(v1.x);
            v1.y = a1.y * inv; v1.y = v1.y > 0.f ? v1.y : expm1f(v1.y);
            v1.z = a1.z * inv; v1.z = v1.z > 0.f ? v1.z : expm1f(v1.z);
            v1.w = a1.w * inv; v1.w = v1.w > 0.f ? v1.w : expm1f(v1.w);
            float4* op = (float4*)(outp + (size_t)n * 64 + sl * 8);
            op[0] = v0; op[1] = v1;
        }
    } else {
        const float4* wp = (const float4*)(whead + sl * 8);
        const float4 w0 = wp[0], w1 = wp[1];
        float v = (a0.x * w0.x + a0.y * w0.y + a0.z * w0.z + a0.w * w0.w
                 + a1.x * w1.x + a1.y * w1.y + a1.z * w1.z + a1.w * w1.w) * inv;
        #pragma unroll
        for (int off = 1; off <= 4; off <<= 1) v += __shfl_xor(v, off, 64);
        if (lane == 0) outp[n] = v + bhead[0];
    }
}

extern "C" void kernel_launch(void* const* d_in, const int* in_sizes, int n_in,
                              void* d_out, int out_size, void* d_ws, size_t ws_size,
                              hipStream_t stream) {
    const float* x      = (const float*)d_in[0];
    const int*   eidx   = (const int*)d_in[1];
    const float* ew     = (const float*)d_in[2];
    const float* tim    = (const float*)d_in[3];
    const float* omega0 = (const float*)d_in[4];
    const float* phase0 = (const float*)d_in[5];
    const float* W0     = (const float*)d_in[6];
    const float* asrc0  = (const float*)d_in[7];
    const float* adst0  = (const float*)d_in[8];
    const float* omega1 = (const float*)d_in[9];
    const float* phase1 = (const float*)d_in[10];
    const float* W1     = (const float*)d_in[11];
    const float* asrc1  = (const float*)d_in[12];
    const float* adst1  = (const float*)d_in[13];
    const float* Whead  = (const float*)d_in[14];
    const float* bhead  = (const float*)d_in[15];
    float* out = (float*)d_out;

    const int* src = eidx;
    const int* dst = eidx + N_EDGES;

    float* ws = (float*)d_ws;
    float* hfeat = ws;                               // N*64
    float* x1    = hfeat + (size_t)N_NODES * 64;     // N*64
    float* s_src = x1    + (size_t)N_NODES * 64;     // N*4
    float* s_dst = s_src + (size_t)N_NODES * 4;      // N*4
    int2* epair  = (int2*)(s_dst + (size_t)N_NODES * 4);   // E (8B each)
    int* deg     = (int*)(epair + (size_t)N_EDGES);  // N
    int* rowptr  = deg + N_NODES;                    // N
    int* cursor  = rowptr + N_NODES;                 // N
    int* bsum    = cursor + N_NODES;                 // 256

    const int tf_grid   = (N_NODES + 63) / 64;       // 782
    const int agg_grid  = (N_NODES + 3) / 4;
    const int sc_grid   = ((N_EDGES + SC_CHUNK - 1) / SC_CHUNK) * NSEG;

    // ---- CSR build (edge structure shared by both layers) ----
    hipMemsetAsync(deg, 0, N_NODES * sizeof(int), stream);
    hist_kernel<<<sc_grid, 256, 0, stream>>>(dst, deg);
    scanA_kernel<<<NB_SCAN, 256, 0, stream>>>(deg, bsum);
    scanB_kernel<<<1, 256, 0, stream>>>(bsum);
    scanC_kernel<<<NB_SCAN, 256, 0, stream>>>(deg, bsum, rowptr, cursor);
    scatter_kernel<<<sc_grid, 256, 0, stream>>>(dst, src, ew, cursor, epair);

    // ---- layer 0 ----
    transform_kernel<128><<<tf_grid, 256, 0, stream>>>(
        x, tim, omega0, phase0, W0, asrc0, adst0, hfeat, s_src, s_dst);
    aggregate_kernel<0><<<agg_grid, 256, 0, stream>>>(
        rowptr, deg, epair, s_src, s_dst, hfeat, Whead, bhead, x1);

    // ---- layer 1 (+ fused linear head) ----
    transform_kernel<64><<<tf_grid, 256, 0, stream>>>(
        x1, tim, omega1, phase1, W1, asrc1, adst1, hfeat, s_src, s_dst);
    aggregate_kernel<1><<<agg_grid, 256, 0, stream>>>(
        rowptr, deg, epair, s_src, s_dst, hfeat, Whead, bhead, out);
}

// Round 12
// 277.401 us; speedup vs baseline: 1.2293x; 1.2293x over previous
//
#include <hip/hip_runtime.h>
#include <hip/hip_bf16.h>
#include <math.h>

#define N_NODES 50000
#define N_EDGES 1600000
#define TE 64
#define LOG2E 1.44269504088896340736f
#define NBK 196            // dst buckets: bucket = dst >> 8 (256 nodes each)
#define BIN_CHUNK 2048
#define BIN_GRID ((N_EDGES + BIN_CHUNK - 1) / BIN_CHUNK)   // 782

// ---------------- node transform ----------------
// h = concat(x, cos(t*omega+phase)) @ W ; also s_src[n,h], s_dst[n,h] (pre-scaled
// by log2e). Register-tiled GEMM: block = 64 nodes x 64 cols, 256 thr = 16x16,
// thread tile 4 nodes x 4 cols.
template<int IN_DIM>
__global__ __launch_bounds__(256) void transform_kernel(
    const float* __restrict__ xin, const float* __restrict__ tim,
    const float* __restrict__ omega, const float* __restrict__ phase,
    const float* __restrict__ W, const float* __restrict__ asrc,
    const float* __restrict__ adst,
    float* __restrict__ hfeat, float* __restrict__ s_src, float* __restrict__ s_dst)
{
    constexpr int K = IN_DIM + TE;
    constexpr int KC = 32;             // k-chunk
    constexpr int NCH = K / KC;
    constexpr int BN = 64;             // nodes per block
    __shared__ float aS[KC][68];       // transposed a-chunk (padded row: 272B)
    __shared__ float wS[KC][64];
    __shared__ float tS[BN];

    const int tid = threadIdx.x;
    const int base = blockIdx.x * BN;

    if (tid < BN) {
        int n = base + tid;
        tS[tid] = (n < N_NODES) ? tim[n] : 0.f;
    }

    const int ty = tid >> 4;           // node quad: nodes ty*4 .. ty*4+3
    const int tx = tid & 15;           // col slot: cols tx*4 .. tx*4+3

    float acc[4][4] = {};

    for (int ch = 0; ch < NCH; ++ch) {
        const int kg0 = ch * KC;
        __syncthreads();               // previous chunk fully consumed

        // stage W chunk: 32x64 floats = 512 float4, 2 per thread (coalesced)
        #pragma unroll
        for (int j = 0; j < 2; ++j) {
            int idx = tid + j * 256;                    // float4 index
            int kk = idx >> 4, c4 = idx & 15;
            *(float4*)&wS[kk][c4 * 4] =
                ((const float4*)(W + (size_t)(kg0 + kk) * 64))[c4];
        }

        // stage a chunk (transposed)
        if (kg0 < IN_DIM) {
            #pragma unroll
            for (int j = 0; j < 2; ++j) {
                int idx = tid + j * 256;
                int nl = idx >> 3, kk = (idx & 7) * 4;
                int n = base + nl;
                float4 v = (n < N_NODES)
                    ? ((const float4*)(xin + (size_t)n * IN_DIM + kg0))[idx & 7]
                    : make_float4(0.f, 0.f, 0.f, 0.f);
                aS[kk + 0][nl] = v.x;
                aS[kk + 1][nl] = v.y;
                aS[kk + 2][nl] = v.z;
                aS[kk + 3][nl] = v.w;
            }
        } else {
            #pragma unroll
            for (int j = 0; j < 8; ++j) {
                int idx = tid + j * 256;
                int kk = idx >> 6, nl = idx & 63;
                int kg = kg0 + kk - IN_DIM;
                aS[kk][nl] = cosf(tS[nl] * omega[kg] + phase[kg]);
            }
        }
        __syncthreads();

        #pragma unroll
        for (int k = 0; k < KC; ++k) {
            const float4 av = *(const float4*)&aS[k][ty * 4];
            const float4 wv = *(const float4*)&wS[k][tx * 4];
            acc[0][0] = fmaf(av.x, wv.x, acc[0][0]);
            acc[0][1] = fmaf(av.x, wv.y, acc[0][1]);
            acc[0][2] = fmaf(av.x, wv.z, acc[0][2]);
            acc[0][3] = fmaf(av.x, wv.w, acc[0][3]);
            acc[1][0] = fmaf(av.y, wv.x, acc[1][0]);
            acc[1][1] = fmaf(av.y, wv.y, acc[1][1]);
            acc[1][2] = fmaf(av.y, wv.z, acc[1][2]);
            acc[1][3] = fmaf(av.y, wv.w, acc[1][3]);
            acc[2][0] = fmaf(av.z, wv.x, acc[2][0]);
            acc[2][1] = fmaf(av.z, wv.y, acc[2][1]);
            acc[2][2] = fmaf(av.z, wv.z, acc[2][2]);
            acc[2][3] = fmaf(av.z, wv.w, acc[2][3]);
            acc[3][0] = fmaf(av.w, wv.x, acc[3][0]);
            acc[3][1] = fmaf(av.w, wv.y, acc[3][1]);
            acc[3][2] = fmaf(av.w, wv.z, acc[3][2]);
            acc[3][3] = fmaf(av.w, wv.w, acc[3][3]);
        }
    }

    // epilogue: hfeat stores + per-head scores
    const float4 as = ((const float4*)asrc)[tx];
    const float4 ad = ((const float4*)adst)[tx];
    #pragma unroll
    for (int j = 0; j < 4; ++j) {
        const int n = base + ty * 4 + j;
        if (n < N_NODES) {
            *(float4*)(hfeat + (size_t)n * 64 + tx * 4) =
                make_float4(acc[j][0], acc[j][1], acc[j][2], acc[j][3]);
        }
        float vs = acc[j][0] * as.x + acc[j][1] * as.y
                 + acc[j][2] * as.z + acc[j][3] * as.w;
        float vd = acc[j][0] * ad.x + acc[j][1] * ad.y
                 + acc[j][2] * ad.z + acc[j][3] * ad.w;
        vs += __shfl_xor(vs, 1, 64); vs += __shfl_xor(vs, 2, 64);
        vd += __shfl_xor(vd, 1, 64); vd += __shfl_xor(vd, 2, 64);
        if ((tx & 3) == 0 && n < N_NODES) {
            s_src[n * 4 + (tx >> 2)] = vs * LOG2E;   // exp2 domain
            s_dst[n * 4 + (tx >> 2)] = vd * LOG2E;
        }
    }
}

// ---------------- CSR build: two-level bucket sort ----------------
// Bucket = dst>>8 (196 buckets x 256 nodes). All random writes are confined
// to windows owned by a SINGLE block (single CU / single L2) -> structural
// write merging, no dependence on block->XCD mapping.

// count bucket sizes (LDS hist, 196 global atomics per block)
__global__ __launch_bounds__(256) void bhist_kernel(
    const int* __restrict__ dst, int* __restrict__ bcnt)
{
    __shared__ int c[NBK];
    for (int t = threadIdx.x; t < NBK; t += 256) c[t] = 0;
    __syncthreads();
    const int base = blockIdx.x * BIN_CHUNK;
    const int end = (base + BIN_CHUNK < N_EDGES) ? base + BIN_CHUNK : N_EDGES;
    for (int e = base + threadIdx.x; e < end; e += 256)
        atomicAdd(&c[dst[e] >> 8], 1);
    __syncthreads();
    for (int t = threadIdx.x; t < NBK; t += 256)
        if (c[t]) atomicAdd(bcnt + t, c[t]);
}

// exclusive scan of bucket counts -> bstart[0..NBK] ; init tails
__global__ __launch_bounds__(256) void bscan_kernel(
    const int* __restrict__ bcnt, int* __restrict__ bstart, int* __restrict__ tail)
{
    __shared__ int s[256];
    const int t = threadIdx.x;
    int v = (t < NBK) ? bcnt[t] : 0;
    s[t] = v;
    __syncthreads();
    #pragma unroll
    for (int off = 1; off < 256; off <<= 1) {
        int u = (t >= off) ? s[t - off] : 0;
        __syncthreads();
        s[t] += u;
        __syncthreads();
    }
    int excl = s[t] - v;
    if (t < NBK) { bstart[t] = excl; tail[t] = excl; }
    if (t == NBK - 1) bstart[NBK] = s[t];
}

// bin edges into bucket regions. Per 2048-edge chunk: LDS-hist ranks, ONE
// global tail atomic per bucket, then writes to 196 contiguous run tails
// (~12KB active window -> L2-merged).
__global__ __launch_bounds__(256) void bin_kernel(
    const int* __restrict__ dst, const int* __restrict__ src,
    const float* __restrict__ ew,
    int* __restrict__ tail, int* __restrict__ rdst, int2* __restrict__ rpair)
{
    __shared__ int cnt[NBK];
    __shared__ int gbase[NBK];
    const int base = blockIdx.x * BIN_CHUNK;
    for (int t = threadIdx.x; t < NBK; t += 256) cnt[t] = 0;
    __syncthreads();

    int d[8], sv[8], rk[8];
    float w[8];
    #pragma unroll
    for (int k = 0; k < 8; ++k) {
        const int e = base + k * 256 + threadIdx.x;
        if (e < N_EDGES) {
            d[k] = dst[e]; sv[k] = src[e]; w[k] = ew[e];
            rk[k] = atomicAdd(&cnt[d[k] >> 8], 1);
        }
    }
    __syncthreads();
    for (int t = threadIdx.x; t < NBK; t += 256)
        gbase[t] = cnt[t] ? atomicAdd(tail + t, cnt[t]) : 0;
    __syncthreads();
    #pragma unroll
    for (int k = 0; k < 8; ++k) {
        const int e = base + k * 256 + threadIdx.x;
        if (e < N_EDGES) {
            const int pos = gbase[d[k] >> 8] + rk[k];
            rdst[pos] = d[k];
            rpair[pos] = make_int2(sv[k], __float_as_int(w[k]));
        }
    }
}

// one block per bucket: build deg/rowptr locally (LDS hist+scan; no global
// hist kernel needed) then place epair via LDS cursors. Random 8B writes are
// confined to this block's ~64KB epair slice -> merged in its own L2.
__global__ __launch_bounds__(256) void place_kernel(
    const int* __restrict__ bstart, const int* __restrict__ rdst,
    const int2* __restrict__ rpair,
    int* __restrict__ deg, int* __restrict__ rowptr, int2* __restrict__ epair)
{
    __shared__ int ldeg[256];
    __shared__ int ls[256];
    __shared__ int lcur[256];
    const int t = threadIdx.x;
    const int b = blockIdx.x;
    const int lo = bstart[b], hi = bstart[b + 1];
    const int nbase = b << 8;

    ldeg[t] = 0;
    __syncthreads();
    for (int i = lo + t; i < hi; i += 256)
        atomicAdd(&ldeg[rdst[i] & 255], 1);
    __syncthreads();

    const int v = ldeg[t];
    ls[t] = v;
    __syncthreads();
    #pragma unroll
    for (int off = 1; off < 256; off <<= 1) {
        int u = (t >= off) ? ls[t - off] : 0;
        __syncthreads();
        ls[t] += u;
        __syncthreads();
    }
    const int excl = ls[t] - v + lo;
    const int n = nbase + t;
    if (n < N_NODES) { rowptr[n] = excl; deg[n] = v; }
    lcur[t] = excl;
    __syncthreads();

    for (int i = lo + t; i < hi; i += 256) {
        const int d = rdst[i];
        const int pos = atomicAdd(&lcur[d & 255], 1);
        epair[pos] = rpair[i];
    }
}

// ---------------- fused per-dst aggregation ----------------
// one wave per node; 8 subgroups x 8 lanes, 8 edges in flight;
// each lane holds 8 features (two float4): cols [sl*8, sl*8+8).
// no max-subtraction (scores O(1), softmax is shift-invariant); exp2 domain.
template<int FINAL>
__global__ __launch_bounds__(256) void aggregate_kernel(
    const int* __restrict__ rowptr, const int* __restrict__ deg,
    const int2* __restrict__ epair,
    const float* __restrict__ s_src, const float* __restrict__ s_dst,
    const float* __restrict__ hfeat,
    const float* __restrict__ whead, const float* __restrict__ bhead,
    float* __restrict__ outp)
{
    const int n = blockIdx.x * 4 + (threadIdx.x >> 6);
    if (n >= N_NODES) return;
    const int lane = threadIdx.x & 63;
    const int g = lane >> 3;          // subgroup (edge slot 0..7)
    const int sl = lane & 7;          // feature octet
    const int hh = sl >> 1;           // head of my features
    const float sdst = s_dst[n * 4 + hh];
    const int beg = rowptr[n];
    const int cnt = deg[n];

    float den = 0.f;
    float4 a0 = make_float4(0.f, 0.f, 0.f, 0.f);
    float4 a1 = make_float4(0.f, 0.f, 0.f, 0.f);

    int i = g;
    int2 ep = (i < cnt) ? epair[beg + i] : make_int2(0, 0);
    while (i < cnt) {
        const int inext = i + 8;
        int2 epn = (inext < cnt) ? epair[beg + inext] : make_int2(0, 0);
        const int s = ep.x;
        const float w = __int_as_float(ep.y);
        float sc = s_src[(size_t)s * 4 + hh] + sdst;
        sc = fmaxf(sc, 0.2f * sc);                       // leaky relu (log2 domain)
        const float p = __builtin_amdgcn_exp2f(sc) * w;
        const float4* hp = (const float4*)(hfeat + (size_t)s * 64 + sl * 8);
        const float4 h0 = hp[0];
        const float4 h1 = hp[1];
        den += p;
        a0.x = fmaf(p, h0.x, a0.x); a0.y = fmaf(p, h0.y, a0.y);
        a0.z = fmaf(p, h0.z, a0.z); a0.w = fmaf(p, h0.w, a0.w);
        a1.x = fmaf(p, h1.x, a1.x); a1.y = fmaf(p, h1.y, a1.y);
        a1.z = fmaf(p, h1.z, a1.z); a1.w = fmaf(p, h1.w, a1.w);
        ep = epn; i = inext;
    }

    // merge 8 subgroups (lane bits 3,4,5)
    #pragma unroll
    for (int off = 8; off <= 32; off <<= 1) {
        den  += __shfl_xor(den, off, 64);
        a0.x += __shfl_xor(a0.x, off, 64); a0.y += __shfl_xor(a0.y, off, 64);
        a0.z += __shfl_xor(a0.z, off, 64); a0.w += __shfl_xor(a0.w, off, 64);
        a1.x += __shfl_xor(a1.x, off, 64); a1.y += __shfl_xor(a1.y, off, 64);
        a1.z += __shfl_xor(a1.z, off, 64); a1.w += __shfl_xor(a1.w, off, 64);
    }

    const float inv = 1.f / (den + 1e-16f);
    if (!FINAL) {
        if (g == 0) {
            float4 v0, v1;
            v0.x = a0.x * inv; v0.x = v0.x > 0.f ? v0.x : expm1f(v0.x);
            v0.y = a0.y * inv; v0.y = v0.y > 0.f ? v0.y : expm1f(v0.y);
            v0.z = a0.z * inv; v0.z = v0.z > 0.f ? v0.z : expm1f(v0.z);
            v0.w = a0.w * inv; v0.w = v0.w > 0.f ? v0.w : expm1f(v0.w);
            v1.x = a1.x * inv; v1.x = v1.x > 0.f ? v1.x : expm1f(v1.x);
            v1.y = a1.y * inv; v1.y = v1.y > 0.f ? v1.y : expm1f(v1.y);
            v1.z = a1.z * inv; v1.z = v1.z > 0.f ? v1.z : expm1f(v1.z);
            v1.w = a1.w * inv; v1.w = v1.w > 0.f ? v1.w : expm1f(v1.w);
            float4* op = (float4*)(outp + (size_t)n * 64 + sl * 8);
            op[0] = v0; op[1] = v1;
        }
    } else {
        const float4* wp = (const float4*)(whead + sl * 8);
        const float4 w0 = wp[0], w1 = wp[1];
        float v = (a0.x * w0.x + a0.y * w0.y + a0.z * w0.z + a0.w * w0.w
                 + a1.x * w1.x + a1.y * w1.y + a1.z * w1.z + a1.w * w1.w) * inv;
        #pragma unroll
        for (int off = 1; off <= 4; off <<= 1) v += __shfl_xor(v, off, 64);
        if (lane == 0) outp[n] = v + bhead[0];
    }
}

extern "C" void kernel_launch(void* const* d_in, const int* in_sizes, int n_in,
                              void* d_out, int out_size, void* d_ws, size_t ws_size,
                              hipStream_t stream) {
    const float* x      = (const float*)d_in[0];
    const int*   eidx   = (const int*)d_in[1];
    const float* ew     = (const float*)d_in[2];
    const float* tim    = (const float*)d_in[3];
    const float* omega0 = (const float*)d_in[4];
    const float* phase0 = (const float*)d_in[5];
    const float* W0     = (const float*)d_in[6];
    const float* asrc0  = (const float*)d_in[7];
    const float* adst0  = (const float*)d_in[8];
    const float* omega1 = (const float*)d_in[9];
    const float* phase1 = (const float*)d_in[10];
    const float* W1     = (const float*)d_in[11];
    const float* asrc1  = (const float*)d_in[12];
    const float* adst1  = (const float*)d_in[13];
    const float* Whead  = (const float*)d_in[14];
    const float* bhead  = (const float*)d_in[15];
    float* out = (float*)d_out;

    const int* src = eidx;
    const int* dst = eidx + N_EDGES;

    float* ws = (float*)d_ws;
    float* hfeat = ws;                               // N*64 (3.2M words)
    float* x1    = hfeat + (size_t)N_NODES * 64;     // N*64 (3.2M words)
    float* s_src = x1    + (size_t)N_NODES * 64;     // N*4
    float* s_dst = s_src + (size_t)N_NODES * 4;      // N*4
    int2* epair  = (int2*)(s_dst + (size_t)N_NODES * 4);   // E int2
    int* deg     = (int*)(epair + (size_t)N_EDGES);  // N
    int* rowptr  = deg + N_NODES;                    // N
    int* bcnt    = rowptr + N_NODES;                 // NBK
    int* bstart  = bcnt + NBK;                       // NBK+1
    int* tail    = bstart + NBK + 1;                 // NBK
    // record arrays alias dead buffers: consumed by place() before their
    // aliases are written (hfeat by transform<128>, x1 by aggregate<0>)
    int*  rdst  = (int*)hfeat;                       // E ints  (<= N*64)
    int2* rpair = (int2*)x1;                         // E int2  (== N*64 words)

    const int tf_grid  = (N_NODES + 63) / 64;        // 782
    const int agg_grid = (N_NODES + 3) / 4;

    // ---- CSR build (two-level bucket sort; shared by both layers) ----
    hipMemsetAsync(bcnt, 0, NBK * sizeof(int), stream);
    bhist_kernel<<<BIN_GRID, 256, 0, stream>>>(dst, bcnt);
    bscan_kernel<<<1, 256, 0, stream>>>(bcnt, bstart, tail);
    bin_kernel<<<BIN_GRID, 256, 0, stream>>>(dst, src, ew, tail, rdst, rpair);
    place_kernel<<<NBK, 256, 0, stream>>>(bstart, rdst, rpair, deg, rowptr, epair);

    // ---- layer 0 ----
    transform_kernel<128><<<tf_grid, 256, 0, stream>>>(
        x, tim, omega0, phase0, W0, asrc0, adst0, hfeat, s_src, s_dst);
    aggregate_kernel<0><<<agg_grid, 256, 0, stream>>>(
        rowptr, deg, epair, s_src, s_dst, hfeat, Whead, bhead, x1);

    // ---- layer 1 (+ fused linear head) ----
    transform_kernel<64><<<tf_grid, 256, 0, stream>>>(
        x1, tim, omega1, phase1, W1, asrc1, adst1, hfeat, s_src, s_dst);
    aggregate_kernel<1><<<agg_grid, 256, 0, stream>>>(
        rowptr, deg, epair, s_src, s_dst, hfeat, Whead, bhead, out);
}